// Round 2
// baseline (1002.257 us; speedup 1.0000x reference)
//
#include <hip/hip_runtime.h>
#include <hip/hip_bf16.h>

// ScAgeNet: encoder (3x [GEMM+BN(eval)+ReLU]) + routed per-cell-type head.
// Inputs/outputs are float32 (per reference); internal compute uses bf16 MFMA
// with f32 accumulation (2% rel tolerance admits this).
//
// Pipeline:
//   repack_x:   x[32768][1985] f32 -> xp[32768][2016] bf16 (zero-pad, aligned)
//   prep_bn:    s=g/sqrt(v+eps), b2=(b-m)*s+be  (per encoder layer)
//   transpose:  Wt[n][k]=W[k][n]*s[n] (bf16, pad k); HW1t[e][n][k]; HW2t[e][m][n]
//   gemm_bias_relu x3 (MFMA 16x16x32 bf16, 128x128 tile)
//   head_kernel: one wave per cell, routed expert, LN via wave shuffles.

typedef __bf16 bf16_t;
typedef bf16_t bf16x8 __attribute__((ext_vector_type(8)));
typedef float  f32x4  __attribute__((ext_vector_type(4)));

#define LDK 40  // LDS row stride in bf16 elems (32 + 8 pad; 2-way bank aliasing max = free)

// ---------------- repack x: f32 [32768][1985] -> bf16 [32768][2016] zero-padded ----------------
__global__ __launch_bounds__(256) void repack_x(const float* __restrict__ x,
                                                bf16_t* __restrict__ xp) {
    const unsigned idx = blockIdx.x * 256u + threadIdx.x;   // 66,060,288 threads exactly
    const unsigned r = idx / 2016u;
    const unsigned c = idx % 2016u;
    float v = (c < 1985u) ? x[(size_t)r * 1985u + c] : 0.f;
    xp[idx] = (bf16_t)v;
}

// ---------------- BN fold: s = g*rsqrt(v+eps); b2 = (b-m)*s + be ----------------
__global__ __launch_bounds__(256) void prep_bn(const float* __restrict__ b,
                                               const float* __restrict__ g,
                                               const float* __restrict__ be,
                                               const float* __restrict__ m,
                                               const float* __restrict__ v,
                                               float* __restrict__ s,
                                               float* __restrict__ b2, int N) {
    int n = blockIdx.x * 256 + threadIdx.x;
    if (n < N) {
        float sv = g[n] * rsqrtf(v[n] + 1e-5f);
        s[n]  = sv;
        b2[n] = (b[n] - m[n]) * sv + be[n];
    }
}

// ---------------- transpose(+scale+pad): out[b][n][kp] = bf16(in[b][k][n]*scale[n]) ----------------
__global__ __launch_bounds__(256) void transpose_scale_pad(const float* __restrict__ in,
                                                           bf16_t* __restrict__ out,
                                                           const float* __restrict__ scale,
                                                           int K, int N, int Kp, int total) {
    const unsigned tid = blockIdx.x * 256u + threadIdx.x;
    if (tid >= (unsigned)total) return;
    const unsigned kchunks = (unsigned)Kp / 8u;
    const unsigned bn = tid / kchunks;
    const unsigned kc = tid % kchunks;
    const unsigned b  = bn / (unsigned)N;
    const unsigned n  = bn % (unsigned)N;
    const unsigned k0 = kc * 8u;
    const float sc = scale ? scale[n] : 1.f;
    bf16x8 v{};
#pragma unroll
    for (int j = 0; j < 8; ++j) {
        unsigned k = k0 + j;
        v[j] = (k < (unsigned)K)
                 ? (bf16_t)(in[((size_t)b * K + k) * N + n] * sc)
                 : (bf16_t)0.f;
    }
    *(bf16x8*)&out[((size_t)b * N + n) * Kp + k0] = v;
}

// ---------------- fused GEMM + bias + ReLU:  C = relu(A @ Bt^T + bias) ----------------
// A: [M][K] bf16 row-major (K mult of 32, rows 16B-aligned)
// Bt: [N][K] bf16 row-major (weights pre-transposed, BN scale folded)
// C: [M][N] bf16. 128x128 tile, BK=32, 256 thr = 4 waves (2x2), 4x4 MFMA tiles/wave.
__global__ __launch_bounds__(256) void gemm_bias_relu(const bf16_t* __restrict__ A,
                                                      const bf16_t* __restrict__ Bt,
                                                      const float* __restrict__ bias,
                                                      bf16_t* __restrict__ C,
                                                      int M, int N, int K) {
    __shared__ bf16_t As[128 * LDK];
    __shared__ bf16_t Bs[128 * LDK];

    const int tid  = threadIdx.x;
    const int bm0  = blockIdx.y * 128;
    const int bn0  = blockIdx.x * 128;
    const int wave = tid >> 6, lane = tid & 63;
    const int wm   = (wave & 1) * 64, wn = (wave >> 1) * 64;
    const int quad = lane >> 4, tq = lane & 15;

    f32x4 acc[4][4] = {};

    // staging: 512 chunks of 8 bf16; thread t handles chunks t and t+256
    const int r0 = tid >> 2;
    const int c0 = (tid & 3) * 8;

    const bf16_t* Ap0 = A + (size_t)(bm0 + r0) * K + c0;
    const bf16_t* Ap1 = A + (size_t)(bm0 + r0 + 64) * K + c0;
    const bf16_t* Bp0 = Bt + (size_t)(bn0 + r0) * K + c0;
    const bf16_t* Bp1 = Bt + (size_t)(bn0 + r0 + 64) * K + c0;

    bf16_t* AsW0 = &As[r0 * LDK + c0];
    bf16_t* AsW1 = &As[(r0 + 64) * LDK + c0];
    bf16_t* BsW0 = &Bs[r0 * LDK + c0];
    bf16_t* BsW1 = &Bs[(r0 + 64) * LDK + c0];

    for (int k0 = 0; k0 < K; k0 += 32) {
        bf16x8 a0 = *(const bf16x8*)(Ap0 + k0);
        bf16x8 a1 = *(const bf16x8*)(Ap1 + k0);
        bf16x8 b0 = *(const bf16x8*)(Bp0 + k0);
        bf16x8 b1 = *(const bf16x8*)(Bp1 + k0);
        __syncthreads();              // previous iter's LDS reads done
        *(bf16x8*)AsW0 = a0;
        *(bf16x8*)AsW1 = a1;
        *(bf16x8*)BsW0 = b0;
        *(bf16x8*)BsW1 = b1;
        __syncthreads();

        bf16x8 af[4], bfr[4];
#pragma unroll
        for (int mt = 0; mt < 4; ++mt)
            af[mt] = *(const bf16x8*)&As[(wm + mt * 16 + tq) * LDK + quad * 8];
#pragma unroll
        for (int nt = 0; nt < 4; ++nt)
            bfr[nt] = *(const bf16x8*)&Bs[(wn + nt * 16 + tq) * LDK + quad * 8];
#pragma unroll
        for (int mt = 0; mt < 4; ++mt)
#pragma unroll
            for (int nt = 0; nt < 4; ++nt)
                acc[mt][nt] = __builtin_amdgcn_mfma_f32_16x16x32_bf16(
                    af[mt], bfr[nt], acc[mt][nt], 0, 0, 0);
    }

    // epilogue: D lane mapping col=lane&15, row=(lane>>4)*4+r  [verified m89/m91]
#pragma unroll
    for (int nt = 0; nt < 4; ++nt) {
        const int col = bn0 + wn + nt * 16 + tq;
        const float bcol = bias[col];
#pragma unroll
        for (int mt = 0; mt < 4; ++mt) {
#pragma unroll
            for (int r = 0; r < 4; ++r) {
                const int row = bm0 + wm + mt * 16 + quad * 4 + r;
                float v = acc[mt][nt][r] + bcol;
                v = v > 0.f ? v : 0.f;
                C[(size_t)row * N + col] = (bf16_t)v;
            }
        }
    }
}

// ---------------- routed head: one wave per cell ----------------
__global__ __launch_bounds__(256) void head_kernel(const bf16_t* __restrict__ feats,
                                                   const int* __restrict__ labels,
                                                   const bf16_t* __restrict__ HW1t,  // [29][128][256] bf16
                                                   const float* __restrict__ Hb1,    // [29][128]
                                                   const float* __restrict__ LG1,
                                                   const float* __restrict__ LB1,
                                                   const bf16_t* __restrict__ HW2t,  // [29][64][128] bf16
                                                   const float* __restrict__ Hb2,    // [29][64]
                                                   const float* __restrict__ LG2,
                                                   const float* __restrict__ LB2,
                                                   const float* __restrict__ HWo,    // [29][64]
                                                   const float* __restrict__ Hbo,    // [29]
                                                   float* __restrict__ out) {
    __shared__ bf16_t sfeats[4][256];
    __shared__ float  st[4][128];

    const int tid = threadIdx.x;
    const int w = tid >> 6, l = tid & 63;
    const int c = blockIdx.x * 4 + w;
    const int e = labels[c];

    if (l < 32)
        *(bf16x8*)&sfeats[w][l * 8] = *(const bf16x8*)&feats[(size_t)c * 256 + l * 8];
    __syncthreads();

    // ---- layer 1: 256 -> 128, lane l computes n=l and n=l+64 ----
    const int n0 = l, n1 = l + 64;
    float acc0 = Hb1[e * 128 + n0];
    float acc1 = Hb1[e * 128 + n1];
    const bf16_t* w0p = HW1t + ((size_t)e * 128 + n0) * 256;
    const bf16_t* w1p = HW1t + ((size_t)e * 128 + n1) * 256;
    for (int k = 0; k < 256; k += 8) {
        bf16x8 f8 = *(const bf16x8*)&sfeats[w][k];
        bf16x8 wa = *(const bf16x8*)&w0p[k];
        bf16x8 wb = *(const bf16x8*)&w1p[k];
#pragma unroll
        for (int j = 0; j < 8; ++j) {
            acc0 += (float)f8[j] * (float)wa[j];
            acc1 += (float)f8[j] * (float)wb[j];
        }
    }
    // LN over 128 (wave reduce, 2 vals/lane)
    float s = acc0 + acc1, sq = acc0 * acc0 + acc1 * acc1;
    for (int off = 32; off; off >>= 1) { s += __shfl_xor(s, off); sq += __shfl_xor(sq, off); }
    float mu   = s * (1.f / 128.f);
    float var  = sq * (1.f / 128.f) - mu * mu;
    float rstd = rsqrtf(var + 1e-5f);
    float t0 = (acc0 - mu) * rstd * LG1[e * 128 + n0] + LB1[e * 128 + n0];
    float t1 = (acc1 - mu) * rstd * LG1[e * 128 + n1] + LB1[e * 128 + n1];
    st[w][n0] = fmaxf(t0, 0.f);
    st[w][n1] = fmaxf(t1, 0.f);
    __syncthreads();

    // ---- layer 2: 128 -> 64, lane l computes m=l ----
    float acc = Hb2[e * 64 + l];
    const bf16_t* w2p = HW2t + ((size_t)e * 64 + l) * 128;
    for (int k = 0; k < 128; k += 8) {
        bf16x8 w8 = *(const bf16x8*)&w2p[k];
#pragma unroll
        for (int j = 0; j < 8; ++j)
            acc += st[w][k + j] * (float)w8[j];
    }
    // LN over 64 (full wave)
    float s2 = acc, sq2 = acc * acc;
    for (int off = 32; off; off >>= 1) { s2 += __shfl_xor(s2, off); sq2 += __shfl_xor(sq2, off); }
    float mu2   = s2 * (1.f / 64.f);
    float var2  = sq2 * (1.f / 64.f) - mu2 * mu2;
    float rstd2 = rsqrtf(var2 + 1e-5f);
    float t2 = (acc - mu2) * rstd2 * LG2[e * 64 + l] + LB2[e * 64 + l];
    t2 = fmaxf(t2, 0.f);

    // ---- output dot ----
    float p = t2 * HWo[e * 64 + l];
    for (int off = 32; off; off >>= 1) p += __shfl_xor(p, off);
    if (l == 0) out[c] = p + Hbo[e];
}

// ---------------- workspace layout (bytes) ----------------
static const size_t OFF_XP    = 0;                  // 132,120,576  (reused: h1 @0, feats @16MB after L0)
static const size_t OFF_H1    = 0;
static const size_t OFF_FEATS = 16777216;
static const size_t OFF_H0    = 132120576;          // 33,554,432
static const size_t OFF_WT0   = 165675008;          // 2,064,384
static const size_t OFF_WT1   = 167739392;          // 262,144
static const size_t OFF_WT2   = 168001536;          // 131,072
static const size_t OFF_B20   = 168132608;          // 2048 (f32)
static const size_t OFF_B21   = 168134656;          // 1024
static const size_t OFF_B22   = 168135680;          // 1024
static const size_t OFF_S0    = 168136704;          // 2048
static const size_t OFF_S1    = 168138752;          // 1024
static const size_t OFF_S2    = 168139776;          // 1024
static const size_t OFF_HW1T  = 168140800;          // 1,900,544
static const size_t OFF_HW2T  = 170041344;          // 475,136
// total ~170.5 MB

extern "C" void kernel_launch(void* const* d_in, const int* in_sizes, int n_in,
                              void* d_out, int out_size, void* d_ws, size_t ws_size,
                              hipStream_t stream) {
    // input order: x, labels, {W,b,g,be,m,v}x3, HW1,Hb1,LG1,LB1,HW2,Hb2,LG2,LB2,HWo,Hbo
    const float* x      = (const float*)d_in[0];
    const int*   labels = (const int*)d_in[1];
    const float* W[3]   = {(const float*)d_in[2], (const float*)d_in[8],  (const float*)d_in[14]};
    const float* bb[3]  = {(const float*)d_in[3], (const float*)d_in[9],  (const float*)d_in[15]};
    const float* g[3]   = {(const float*)d_in[4], (const float*)d_in[10], (const float*)d_in[16]};
    const float* be[3]  = {(const float*)d_in[5], (const float*)d_in[11], (const float*)d_in[17]};
    const float* mm[3]  = {(const float*)d_in[6], (const float*)d_in[12], (const float*)d_in[18]};
    const float* vv[3]  = {(const float*)d_in[7], (const float*)d_in[13], (const float*)d_in[19]};
    const float* HW1 = (const float*)d_in[20];
    const float* Hb1 = (const float*)d_in[21];
    const float* LG1 = (const float*)d_in[22];
    const float* LB1 = (const float*)d_in[23];
    const float* HW2 = (const float*)d_in[24];
    const float* Hb2 = (const float*)d_in[25];
    const float* LG2 = (const float*)d_in[26];
    const float* LB2 = (const float*)d_in[27];
    const float* HWo = (const float*)d_in[28];
    const float* Hbo = (const float*)d_in[29];

    char* ws = (char*)d_ws;
    bf16_t* xp    = (bf16_t*)(ws + OFF_XP);
    bf16_t* h0    = (bf16_t*)(ws + OFF_H0);
    bf16_t* h1    = (bf16_t*)(ws + OFF_H1);
    bf16_t* feats = (bf16_t*)(ws + OFF_FEATS);
    bf16_t* Wt[3] = {(bf16_t*)(ws + OFF_WT0), (bf16_t*)(ws + OFF_WT1), (bf16_t*)(ws + OFF_WT2)};
    float*  b2[3] = {(float*)(ws + OFF_B20), (float*)(ws + OFF_B21), (float*)(ws + OFF_B22)};
    float*  sc[3] = {(float*)(ws + OFF_S0), (float*)(ws + OFF_S1), (float*)(ws + OFF_S2)};
    bf16_t* HW1t  = (bf16_t*)(ws + OFF_HW1T);
    bf16_t* HW2t  = (bf16_t*)(ws + OFF_HW2T);
    float*  outp  = (float*)d_out;

    // 1) repack x into padded, aligned bf16 layout (coalesced f32 reads)
    repack_x<<<258048, 256, 0, stream>>>(x, xp);

    // 2) BN fold
    prep_bn<<<2, 256, 0, stream>>>(bb[0], g[0], be[0], mm[0], vv[0], sc[0], b2[0], 512);
    prep_bn<<<1, 256, 0, stream>>>(bb[1], g[1], be[1], mm[1], vv[1], sc[1], b2[1], 256);
    prep_bn<<<1, 256, 0, stream>>>(bb[2], g[2], be[2], mm[2], vv[2], sc[2], b2[2], 256);

    // 3) weight transposes (+scale for encoder, +pad for layer0)
    transpose_scale_pad<<<504, 256, 0, stream>>>(W[0], Wt[0], sc[0], 1985, 512, 2016, 129024);
    transpose_scale_pad<<<64,  256, 0, stream>>>(W[1], Wt[1], sc[1], 512, 256, 512, 16384);
    transpose_scale_pad<<<32,  256, 0, stream>>>(W[2], Wt[2], sc[2], 256, 256, 256, 8192);
    transpose_scale_pad<<<464, 256, 0, stream>>>(HW1, HW1t, nullptr, 256, 128, 256, 118784);
    transpose_scale_pad<<<116, 256, 0, stream>>>(HW2, HW2t, nullptr, 128, 64, 128, 29696);

    // 4) encoder GEMMs (fused bias+ReLU)
    dim3 blk(256);
    dim3 grid0(512 / 128, 32768 / 128);
    gemm_bias_relu<<<grid0, blk, 0, stream>>>(xp, Wt[0], b2[0], h0, 32768, 512, 2016);
    dim3 grid1(256 / 128, 32768 / 128);
    gemm_bias_relu<<<grid1, blk, 0, stream>>>(h0, Wt[1], b2[1], h1, 32768, 256, 512);
    gemm_bias_relu<<<grid1, blk, 0, stream>>>(h1, Wt[2], b2[2], feats, 32768, 256, 256);

    // 5) routed head
    head_kernel<<<8192, 256, 0, stream>>>(feats, labels, HW1t, Hb1, LG1, LB1,
                                          HW2t, Hb2, LG2, LB2, HWo, Hbo, outp);
}

// Round 3
// 778.187 us; speedup vs baseline: 1.2879x; 1.2879x over previous
//
#include <hip/hip_runtime.h>
#include <hip/hip_bf16.h>

// ScAgeNet: encoder (3x [GEMM+BN(eval)+ReLU]) + routed per-cell-type head.
// f32 in/out; internal bf16 MFMA with f32 accumulation.
//
// Head is label-bucketed: counting-sort cells by label, then MFMA grouped-GEMM
// over <=544 tiles of 64 cells each (one expert per tile), LN via quad shuffles.

typedef __bf16 bf16_t;
typedef bf16_t bf16x8 __attribute__((ext_vector_type(8)));
typedef float  f32x4  __attribute__((ext_vector_type(4)));

#define LDK 40       // encoder LDS row stride (bf16): 32+8 pad
#define MAX_TILES 544
#define T1_LD 136    // head inter-layer LDS stride (128+8)

// ---------------- repack x: f32 [32768][1985] -> bf16 [32768][2016] zero-padded ----------------
__global__ __launch_bounds__(256) void repack_x(const float* __restrict__ x,
                                                bf16_t* __restrict__ xp) {
    const unsigned idx = blockIdx.x * 256u + threadIdx.x;   // 66,060,288 threads exactly
    const unsigned r = idx / 2016u;
    const unsigned c = idx % 2016u;
    float v = (c < 1985u) ? x[(size_t)r * 1985u + c] : 0.f;
    xp[idx] = (bf16_t)v;
}

// ---------------- BN fold ----------------
__global__ __launch_bounds__(256) void prep_bn(const float* __restrict__ b,
                                               const float* __restrict__ g,
                                               const float* __restrict__ be,
                                               const float* __restrict__ m,
                                               const float* __restrict__ v,
                                               float* __restrict__ s,
                                               float* __restrict__ b2, int N) {
    int n = blockIdx.x * 256 + threadIdx.x;
    if (n < N) {
        float sv = g[n] * rsqrtf(v[n] + 1e-5f);
        s[n]  = sv;
        b2[n] = (b[n] - m[n]) * sv + be[n];
    }
}

// ---------------- transpose(+scale+pad): out[b][n][kp] = bf16(in[b][k][n]*scale[n]) ----------------
__global__ __launch_bounds__(256) void transpose_scale_pad(const float* __restrict__ in,
                                                           bf16_t* __restrict__ out,
                                                           const float* __restrict__ scale,
                                                           int K, int N, int Kp, int total) {
    const unsigned tid = blockIdx.x * 256u + threadIdx.x;
    if (tid >= (unsigned)total) return;
    const unsigned kchunks = (unsigned)Kp / 8u;
    const unsigned bn = tid / kchunks;
    const unsigned kc = tid % kchunks;
    const unsigned b  = bn / (unsigned)N;
    const unsigned n  = bn % (unsigned)N;
    const unsigned k0 = kc * 8u;
    const float sc = scale ? scale[n] : 1.f;
    bf16x8 v{};
#pragma unroll
    for (int j = 0; j < 8; ++j) {
        unsigned k = k0 + j;
        v[j] = (k < (unsigned)K)
                 ? (bf16_t)(in[((size_t)b * K + k) * N + n] * sc)
                 : (bf16_t)0.f;
    }
    *(bf16x8*)&out[((size_t)b * N + n) * Kp + k0] = v;
}

// ---------------- fused GEMM + bias + ReLU (MFMA 16x16x32, 128x128 tile) ----------------
__global__ __launch_bounds__(256) void gemm_bias_relu(const bf16_t* __restrict__ A,
                                                      const bf16_t* __restrict__ Bt,
                                                      const float* __restrict__ bias,
                                                      bf16_t* __restrict__ C,
                                                      int M, int N, int K) {
    __shared__ bf16_t As[128 * LDK];
    __shared__ bf16_t Bs[128 * LDK];

    const int tid  = threadIdx.x;
    const int bm0  = blockIdx.y * 128;
    const int bn0  = blockIdx.x * 128;
    const int wave = tid >> 6, lane = tid & 63;
    const int wm   = (wave & 1) * 64, wn = (wave >> 1) * 64;
    const int quad = lane >> 4, tq = lane & 15;

    f32x4 acc[4][4] = {};

    const int r0 = tid >> 2;
    const int c0 = (tid & 3) * 8;

    const bf16_t* Ap0 = A + (size_t)(bm0 + r0) * K + c0;
    const bf16_t* Ap1 = A + (size_t)(bm0 + r0 + 64) * K + c0;
    const bf16_t* Bp0 = Bt + (size_t)(bn0 + r0) * K + c0;
    const bf16_t* Bp1 = Bt + (size_t)(bn0 + r0 + 64) * K + c0;

    bf16_t* AsW0 = &As[r0 * LDK + c0];
    bf16_t* AsW1 = &As[(r0 + 64) * LDK + c0];
    bf16_t* BsW0 = &Bs[r0 * LDK + c0];
    bf16_t* BsW1 = &Bs[(r0 + 64) * LDK + c0];

    for (int k0 = 0; k0 < K; k0 += 32) {
        bf16x8 a0 = *(const bf16x8*)(Ap0 + k0);
        bf16x8 a1 = *(const bf16x8*)(Ap1 + k0);
        bf16x8 b0 = *(const bf16x8*)(Bp0 + k0);
        bf16x8 b1 = *(const bf16x8*)(Bp1 + k0);
        __syncthreads();
        *(bf16x8*)AsW0 = a0;
        *(bf16x8*)AsW1 = a1;
        *(bf16x8*)BsW0 = b0;
        *(bf16x8*)BsW1 = b1;
        __syncthreads();

        bf16x8 af[4], bfr[4];
#pragma unroll
        for (int mt = 0; mt < 4; ++mt)
            af[mt] = *(const bf16x8*)&As[(wm + mt * 16 + tq) * LDK + quad * 8];
#pragma unroll
        for (int nt = 0; nt < 4; ++nt)
            bfr[nt] = *(const bf16x8*)&Bs[(wn + nt * 16 + tq) * LDK + quad * 8];
#pragma unroll
        for (int mt = 0; mt < 4; ++mt)
#pragma unroll
            for (int nt = 0; nt < 4; ++nt)
                acc[mt][nt] = __builtin_amdgcn_mfma_f32_16x16x32_bf16(
                    af[mt], bfr[nt], acc[mt][nt], 0, 0, 0);
    }

#pragma unroll
    for (int nt = 0; nt < 4; ++nt) {
        const int col = bn0 + wn + nt * 16 + tq;
        const float bcol = bias[col];
#pragma unroll
        for (int mt = 0; mt < 4; ++mt) {
#pragma unroll
            for (int r = 0; r < 4; ++r) {
                const int row = bm0 + wm + mt * 16 + quad * 4 + r;
                float v = acc[mt][nt][r] + bcol;
                v = v > 0.f ? v : 0.f;
                C[(size_t)row * N + col] = (bf16_t)v;
            }
        }
    }
}

// ---------------- head bucketing ----------------
__global__ __launch_bounds__(64) void head_init(int* __restrict__ counts) {
    if (threadIdx.x < 32) counts[threadIdx.x] = 0;
}

__global__ __launch_bounds__(256) void head_hist(const int* __restrict__ labels,
                                                 int* __restrict__ counts) {
    __shared__ int h[32];
    if (threadIdx.x < 32) h[threadIdx.x] = 0;
    __syncthreads();
    int c = blockIdx.x * 256 + threadIdx.x;
    atomicAdd(&h[labels[c]], 1);
    __syncthreads();
    if (threadIdx.x < 32) {
        int v = h[threadIdx.x];
        if (v) atomicAdd(&counts[threadIdx.x], v);
    }
}

// single block, 1024 threads: offsets scan + cursor init + tile descriptors
__global__ __launch_bounds__(1024) void head_plan(const int* __restrict__ counts,
                                                  int* __restrict__ cursor,
                                                  int4* __restrict__ descs) {
    __shared__ int offs[30];   // cell offset per expert
    __shared__ int toffs[30];  // tile offset per expert
    if (threadIdx.x == 0) {
        int off = 0, toff = 0;
        for (int e = 0; e < 29; ++e) {
            offs[e] = off; toffs[e] = toff;
            int n = counts[e];
            off += n; toff += (n + 63) >> 6;
        }
        offs[29] = off; toffs[29] = toff;
    }
    __syncthreads();
    if (threadIdx.x < 29) cursor[threadIdx.x] = offs[threadIdx.x];
    int t = threadIdx.x;
    if (t < MAX_TILES) {
        int4 d = make_int4(0, 0, 0, 0);
        if (t < toffs[29]) {
            int e = 0;
            while (toffs[e + 1] <= t) ++e;   // <=29 iters
            int ti = t - toffs[e];
            int n  = counts[e];
            d.x = e;
            d.y = offs[e] + ti * 64;
            d.z = min(64, n - ti * 64);
        }
        descs[t] = d;
    }
}

__global__ __launch_bounds__(256) void head_scatter(const int* __restrict__ labels,
                                                    int* __restrict__ cursor,
                                                    int* __restrict__ perm) {
    int c = blockIdx.x * 256 + threadIdx.x;
    int p = atomicAdd(&cursor[labels[c]], 1);
    perm[p] = c;
}

// ---------------- MFMA head: one block per 64-cell tile of one expert ----------------
__global__ __launch_bounds__(256) void head_mfma(const bf16_t* __restrict__ feats,
                                                 const int* __restrict__ perm,
                                                 const int4* __restrict__ descs,
                                                 const bf16_t* __restrict__ HW1t,  // [29][128][256]
                                                 const float* __restrict__ Hb1,
                                                 const float* __restrict__ LG1,
                                                 const float* __restrict__ LB1,
                                                 const bf16_t* __restrict__ HW2t,  // [29][64][128]
                                                 const float* __restrict__ Hb2,
                                                 const float* __restrict__ LG2,
                                                 const float* __restrict__ LB2,
                                                 const float* __restrict__ HWo,    // [29][64]
                                                 const float* __restrict__ Hbo,    // [29]
                                                 float* __restrict__ out) {
    __shared__ bf16_t t1s[64 * T1_LD];

    const int4 d = descs[blockIdx.x];
    const int e = d.x, start = d.y, count = d.z;
    if (count == 0) return;          // uniform per block

    const int tid = threadIdx.x, w = tid >> 6, lane = tid & 63;
    const int tq = lane & 15, quad = lane >> 4;
    const int m0 = w * 16;           // wave's 16 cells within the 64-cell tile

    // gathered A row for this lane (clamped padding rows -> valid dup, never stored)
    const int am = m0 + tq;
    const int ridx = perm[start + ((am < count) ? am : 0)];
    const bf16_t* arow = feats + (size_t)ridx * 256;

    // ---- layer 1: [16 x 256] @ [256 x 128] ----
    const bf16_t* w1 = HW1t + (size_t)e * 128 * 256;
    f32x4 acc1[8] = {};
#pragma unroll
    for (int ks = 0; ks < 8; ++ks) {
        bf16x8 a = *(const bf16x8*)(arow + ks * 32 + quad * 8);
#pragma unroll
        for (int nt = 0; nt < 8; ++nt) {
            bf16x8 b = *(const bf16x8*)(w1 + (size_t)(nt * 16 + tq) * 256 + ks * 32 + quad * 8);
            acc1[nt] = __builtin_amdgcn_mfma_f32_16x16x32_bf16(a, b, acc1[nt], 0, 0, 0);
        }
    }

    // bias + LN(128) + ReLU -> t1s (quad owns its 4 cells' rows entirely)
    float s1[4] = {}, q1[4] = {};
#pragma unroll
    for (int nt = 0; nt < 8; ++nt) {
        float hb = Hb1[e * 128 + nt * 16 + tq];
#pragma unroll
        for (int r = 0; r < 4; ++r) {
            float v = acc1[nt][r] + hb;
            acc1[nt][r] = v;
            s1[r] += v; q1[r] += v * v;
        }
    }
#pragma unroll
    for (int off = 1; off < 16; off <<= 1)
#pragma unroll
        for (int r = 0; r < 4; ++r) {
            s1[r] += __shfl_xor(s1[r], off);
            q1[r] += __shfl_xor(q1[r], off);
        }
    float mu1[4], rs1[4];
#pragma unroll
    for (int r = 0; r < 4; ++r) {
        mu1[r] = s1[r] * (1.f / 128.f);
        rs1[r] = rsqrtf(q1[r] * (1.f / 128.f) - mu1[r] * mu1[r] + 1e-5f);
    }
#pragma unroll
    for (int nt = 0; nt < 8; ++nt) {
        const int col = nt * 16 + tq;
        const float lg = LG1[e * 128 + col], lb = LB1[e * 128 + col];
#pragma unroll
        for (int r = 0; r < 4; ++r) {
            float t = (acc1[nt][r] - mu1[r]) * rs1[r] * lg + lb;
            t1s[(m0 + quad * 4 + r) * T1_LD + col] = (bf16_t)fmaxf(t, 0.f);
        }
    }
    __syncthreads();

    // ---- layer 2: [16 x 128] @ [128 x 64] ----
    const bf16_t* w2 = HW2t + (size_t)e * 64 * 128;
    f32x4 acc2[4] = {};
#pragma unroll
    for (int ks = 0; ks < 4; ++ks) {
        bf16x8 a = *(const bf16x8*)&t1s[(m0 + tq) * T1_LD + ks * 32 + quad * 8];
#pragma unroll
        for (int nt = 0; nt < 4; ++nt) {
            bf16x8 b = *(const bf16x8*)(w2 + (size_t)(nt * 16 + tq) * 128 + ks * 32 + quad * 8);
            acc2[nt] = __builtin_amdgcn_mfma_f32_16x16x32_bf16(a, b, acc2[nt], 0, 0, 0);
        }
    }

    // bias + LN(64) + ReLU + dot(HWo)
    float s2[4] = {}, q2[4] = {};
#pragma unroll
    for (int nt = 0; nt < 4; ++nt) {
        float hb = Hb2[e * 64 + nt * 16 + tq];
#pragma unroll
        for (int r = 0; r < 4; ++r) {
            float v = acc2[nt][r] + hb;
            acc2[nt][r] = v;
            s2[r] += v; q2[r] += v * v;
        }
    }
#pragma unroll
    for (int off = 1; off < 16; off <<= 1)
#pragma unroll
        for (int r = 0; r < 4; ++r) {
            s2[r] += __shfl_xor(s2[r], off);
            q2[r] += __shfl_xor(q2[r], off);
        }
    float p[4] = {};
#pragma unroll
    for (int nt = 0; nt < 4; ++nt) {
        const int col = nt * 16 + tq;
        const float lg = LG2[e * 64 + col], lb = LB2[e * 64 + col];
        const float wo = HWo[e * 64 + col];
#pragma unroll
        for (int r = 0; r < 4; ++r) {
            float mu = s2[r] * (1.f / 64.f);
            float rs = rsqrtf(q2[r] * (1.f / 64.f) - mu * mu + 1e-5f);
            float t = (acc2[nt][r] - mu) * rs * lg + lb;
            p[r] += fmaxf(t, 0.f) * wo;
        }
    }
#pragma unroll
    for (int off = 1; off < 16; off <<= 1)
#pragma unroll
        for (int r = 0; r < 4; ++r) p[r] += __shfl_xor(p[r], off);

    if (tq == 0) {
        const float hbo = Hbo[e];
#pragma unroll
        for (int r = 0; r < 4; ++r) {
            int m = m0 + quad * 4 + r;
            if (m < count) out[perm[start + m]] = p[r] + hbo;
        }
    }
}

// ---------------- workspace layout (bytes) ----------------
static const size_t OFF_XP    = 0;                  // xp: 132,120,576 (dead after L0)
static const size_t OFF_H1    = 0;                  // h1 reuses xp space
static const size_t OFF_FEATS = 16777216;
static const size_t OFF_H0    = 132120576;          // h0: 33,554,432 (dead after L1 -> reused for sort)
static const size_t OFF_CNT   = 132120576;          // 128 B (after L1)
static const size_t OFF_CUR   = 132120832;          // 128 B
static const size_t OFF_DESC  = 132121088;          // 544*16 = 8704 B
static const size_t OFF_PERM  = 132136960;          // 131072 B
static const size_t OFF_WT0   = 165675008;          // 2,064,384
static const size_t OFF_WT1   = 167739392;
static const size_t OFF_WT2   = 168001536;
static const size_t OFF_B20   = 168132608;
static const size_t OFF_B21   = 168134656;
static const size_t OFF_B22   = 168135680;
static const size_t OFF_S0    = 168136704;
static const size_t OFF_S1    = 168138752;
static const size_t OFF_S2    = 168139776;
static const size_t OFF_HW1T  = 168140800;          // 1,900,544
static const size_t OFF_HW2T  = 170041344;          // 475,136

extern "C" void kernel_launch(void* const* d_in, const int* in_sizes, int n_in,
                              void* d_out, int out_size, void* d_ws, size_t ws_size,
                              hipStream_t stream) {
    const float* x      = (const float*)d_in[0];
    const int*   labels = (const int*)d_in[1];
    const float* W[3]   = {(const float*)d_in[2], (const float*)d_in[8],  (const float*)d_in[14]};
    const float* bb[3]  = {(const float*)d_in[3], (const float*)d_in[9],  (const float*)d_in[15]};
    const float* g[3]   = {(const float*)d_in[4], (const float*)d_in[10], (const float*)d_in[16]};
    const float* be[3]  = {(const float*)d_in[5], (const float*)d_in[11], (const float*)d_in[17]};
    const float* mm[3]  = {(const float*)d_in[6], (const float*)d_in[12], (const float*)d_in[18]};
    const float* vv[3]  = {(const float*)d_in[7], (const float*)d_in[13], (const float*)d_in[19]};
    const float* HW1 = (const float*)d_in[20];
    const float* Hb1 = (const float*)d_in[21];
    const float* LG1 = (const float*)d_in[22];
    const float* LB1 = (const float*)d_in[23];
    const float* HW2 = (const float*)d_in[24];
    const float* Hb2 = (const float*)d_in[25];
    const float* LG2 = (const float*)d_in[26];
    const float* LB2 = (const float*)d_in[27];
    const float* HWo = (const float*)d_in[28];
    const float* Hbo = (const float*)d_in[29];

    char* ws = (char*)d_ws;
    bf16_t* xp    = (bf16_t*)(ws + OFF_XP);
    bf16_t* h0    = (bf16_t*)(ws + OFF_H0);
    bf16_t* h1    = (bf16_t*)(ws + OFF_H1);
    bf16_t* feats = (bf16_t*)(ws + OFF_FEATS);
    bf16_t* Wt[3] = {(bf16_t*)(ws + OFF_WT0), (bf16_t*)(ws + OFF_WT1), (bf16_t*)(ws + OFF_WT2)};
    float*  b2[3] = {(float*)(ws + OFF_B20), (float*)(ws + OFF_B21), (float*)(ws + OFF_B22)};
    float*  sc[3] = {(float*)(ws + OFF_S0), (float*)(ws + OFF_S1), (float*)(ws + OFF_S2)};
    bf16_t* HW1t  = (bf16_t*)(ws + OFF_HW1T);
    bf16_t* HW2t  = (bf16_t*)(ws + OFF_HW2T);
    int*    cnt   = (int*)(ws + OFF_CNT);
    int*    cur   = (int*)(ws + OFF_CUR);
    int4*   descs = (int4*)(ws + OFF_DESC);
    int*    perm  = (int*)(ws + OFF_PERM);
    float*  outp  = (float*)d_out;

    // 1) repack x
    repack_x<<<258048, 256, 0, stream>>>(x, xp);

    // 2) BN fold + weight transposes
    prep_bn<<<2, 256, 0, stream>>>(bb[0], g[0], be[0], mm[0], vv[0], sc[0], b2[0], 512);
    prep_bn<<<1, 256, 0, stream>>>(bb[1], g[1], be[1], mm[1], vv[1], sc[1], b2[1], 256);
    prep_bn<<<1, 256, 0, stream>>>(bb[2], g[2], be[2], mm[2], vv[2], sc[2], b2[2], 256);
    transpose_scale_pad<<<504, 256, 0, stream>>>(W[0], Wt[0], sc[0], 1985, 512, 2016, 129024);
    transpose_scale_pad<<<64,  256, 0, stream>>>(W[1], Wt[1], sc[1], 512, 256, 512, 16384);
    transpose_scale_pad<<<32,  256, 0, stream>>>(W[2], Wt[2], sc[2], 256, 256, 256, 8192);
    transpose_scale_pad<<<464, 256, 0, stream>>>(HW1, HW1t, nullptr, 256, 128, 256, 118784);
    transpose_scale_pad<<<116, 256, 0, stream>>>(HW2, HW2t, nullptr, 128, 64, 128, 29696);

    // 3) encoder GEMMs
    dim3 blk(256);
    dim3 grid0(512 / 128, 32768 / 128);
    gemm_bias_relu<<<grid0, blk, 0, stream>>>(xp, Wt[0], b2[0], h0, 32768, 512, 2016);
    dim3 grid1(256 / 128, 32768 / 128);
    gemm_bias_relu<<<grid1, blk, 0, stream>>>(h0, Wt[1], b2[1], h1, 32768, 256, 512);

    // 4) bucketing (h0 dead now -> its region holds sort structures)
    head_init<<<1, 64, 0, stream>>>(cnt);
    head_hist<<<128, 256, 0, stream>>>(labels, cnt);
    head_plan<<<1, 1024, 0, stream>>>(cnt, cur, descs);
    head_scatter<<<128, 256, 0, stream>>>(labels, cur, perm);

    gemm_bias_relu<<<grid1, blk, 0, stream>>>(h1, Wt[2], b2[2], feats, 32768, 256, 256);

    // 5) MFMA head over bucketed tiles
    head_mfma<<<MAX_TILES, 256, 0, stream>>>(feats, perm, descs, HW1t, Hb1, LG1, LB1,
                                             HW2t, Hb2, LG2, LB2, HWo, Hbo, outp);
}